// Round 1
// baseline (90.269 us; speedup 1.0000x reference)
//
#include <hip/hip_runtime.h>
#include <float.h>

// MultiTierLoss: B=4096 rows, D=1000 cols, fp32.
// Tier0: rel [0,50) vs neg [475,1000), /26250
// Tier1: rel [475,525) vs neg [950,1000), /2500
// GT:    rel [0,n) vs neg [n,1000), *2/1000, n<=8 (wave-uniform per row)
//
// R7 = R6 compute (unchanged), reduction re-plumbed to avoid d_ws entirely.
// Rocprof showed the timed window is dominated by a 44 us, 256 MiB
// fillBufferAligned = harness workspace re-poison. Theory: poison is tied to
// d_ws usage. This version touches ONLY d_in/d_out:
//   - tiny zero_out kernel resets d_out (stream order guarantees ordering)
//   - each block does ONE fire-and-forget atomicAdd(out, partial/4096)
//   - second reduce dispatch deleted (~4 us saved regardless)
// (R3/R5's +10..19 us was fan-in WITH readback/fences; no-return atomics from
// staggered blocks should mostly hide under kernel drain.)

#define BQ 4096
#define DQ 1000
#define GRID 1024   // 4 rows/block, 1 row/wave

__device__ __forceinline__ float bitonic_sort64(float v, int lane) {
    #pragma unroll
    for (int size = 2; size <= 64; size <<= 1) {
        #pragma unroll
        for (int stride = size >> 1; stride > 0; stride >>= 1) {
            float other = __shfl_xor(v, stride, 64);
            bool keep_min = (((lane & stride) == 0) == ((lane & size) == 0));
            v = keep_min ? fminf(v, other) : fmaxf(v, other);
        }
    }
    return v;   // ascending across lanes 0..63
}

__device__ __forceinline__ float excl_scan50(float sv, int lane) {
    float x = (lane < 50) ? sv : 0.0f;   // zero the FLT_MAX pads
    float inc = x;
    #pragma unroll
    for (int off = 1; off < 64; off <<= 1) {
        float t = __shfl_up(inc, off, 64);
        if (lane >= off) inc += t;
    }
    return inc - x;   // lane c holds sum of sorted[0..c)
}

// sum_i relu(x - sorted_i) = c*x - pre[c], c = #{sorted_i < x} (<=50)
__device__ __forceinline__ float sorted_relu_sum(float x, float sv, float pre) {
    int c = 0;
    #pragma unroll
    for (int st = 32; st >= 1; st >>= 1) {
        float scv = __shfl(sv, c + st - 1, 64);   // pads=FLT_MAX cap c at 50
        c += (scv < x) ? st : 0;
    }
    float p = __shfl(pre, c, 64);
    return (float)c * x - p;
}

__global__ __launch_bounds__(64) void zero_out(float* __restrict__ out) {
    if (threadIdx.x == 0) out[0] = 0.0f;
}

__global__ __launch_bounds__(256) void mtl_rows(const float* __restrict__ scores,
                                               const int* __restrict__ labels,
                                               float* __restrict__ out) {
    const int tid  = threadIdx.x;
    const int lane = tid & 63;
    const int w    = tid >> 6;
    const int row  = blockIdx.x * 4 + w;
    const float* sr = scores + (size_t)row * DQ;

    __shared__ float wsum[4];

    // round-robin register row: q[t] = s[lane + 64t]
    float q[16];
    #pragma unroll
    for (int t = 0; t < 15; ++t) q[t] = sr[lane + 64 * t];
    q[15] = (lane < 40) ? sr[960 + lane] : 0.0f;   // j=960+lane < 1000

    // n from first 8 labels via ballot (n <= MAX_REL = 8 by construction)
    int lv = -1;
    if (lane < 8) lv = labels[(size_t)row * DQ + lane];
    const int n = __popcll(__ballot(lv > -1));     // wave-uniform

    // tier0 relatives s[0..50) == q[0] on lanes 0..49
    float sv0  = bitonic_sort64((lane < 50) ? q[0] : FLT_MAX, lane);
    float pre0 = excl_scan50(sv0, lane);

    // tier1 relatives s[475..525)
    float r1 = FLT_MAX;
    if (lane < 50) r1 = sr[475 + lane];
    float sv1  = bitonic_sort64(r1, lane);
    float pre1 = excl_scan50(sv1, lane);

    // ---- GT: x_j = 1 + s_j, relatives s[0..n) broadcast from q[0]
    float tgt[16];
    #pragma unroll
    for (int t = 0; t < 16; ++t) tgt[t] = 0.0f;
    for (int k = 0; k < n; ++k) {                  // uniform trip count
        float gk = 1.0f - __shfl(q[0], k, 64);
        #pragma unroll
        for (int t = 0; t < 16; ++t) tgt[t] += fmaxf(q[t] + gk, 0.0f);
    }
    float gts = (lane >= n) ? tgt[0] : 0.0f;       // slot 0: j=lane, need j>=n
    #pragma unroll
    for (int t = 1; t < 15; ++t) gts += tgt[t];    // j in [64,960) all valid
    gts += (lane < 40) ? tgt[15] : 0.0f;           // j<1000
    float acc = gts * (2.0f / 1000.0f);

    // ---- tier0: negatives j in [475,1000) -> slots 7..15
    float t0s = 0.0f;
    #pragma unroll
    for (int t = 7; t < 16; ++t) {
        float x = 1.0f + q[t];
        float val = sorted_relu_sum(x, sv0, pre0);
        bool act = (t == 7) ? (lane >= 27)         // j=448+lane >= 475
                 : (t == 15) ? (lane < 40)         // j=960+lane < 1000
                 : true;
        t0s += act ? val : 0.0f;
    }
    acc += t0s * (1.0f / 26250.0f);

    // ---- tier1: negatives j in [950,1000) -> slots 14 (lane>=54), 15 (lane<40)
    {
        float v14 = sorted_relu_sum(1.0f + q[14], sv1, pre1);
        acc += (lane >= 54) ? v14 * (1.0f / 2500.0f) : 0.0f;
        float v15 = sorted_relu_sum(1.0f + q[15], sv1, pre1);
        acc += (lane < 40) ? v15 * (1.0f / 2500.0f) : 0.0f;
    }

    // ---- wave reduce, fold the block's 4 waves, ONE fire-and-forget atomic
    #pragma unroll
    for (int off = 32; off > 0; off >>= 1) acc += __shfl_down(acc, off, 64);
    if (lane == 0) wsum[w] = acc;
    __syncthreads();
    if (tid == 0) {
        float bsum = wsum[0] + wsum[1] + wsum[2] + wsum[3];
        atomicAdd(out, bsum * (1.0f / (float)BQ));   // no readback, no fence
    }
}

extern "C" void kernel_launch(void* const* d_in, const int* in_sizes, int n_in,
                              void* d_out, int out_size, void* d_ws, size_t ws_size,
                              hipStream_t stream) {
    const float* scores = (const float*)d_in[0];
    const int*   labels = (const int*)d_in[1];
    float* out = (float*)d_out;
    (void)d_ws; (void)ws_size;   // deliberately untouched — see header comment

    zero_out<<<1, 64, 0, stream>>>(out);
    mtl_rows<<<GRID, 256, 0, stream>>>(scores, labels, out);
}

// Round 2
// 84.720 us; speedup vs baseline: 1.0655x; 1.0655x over previous
//
#include <hip/hip_runtime.h>
#include <float.h>

// MultiTierLoss: B=4096 rows, D=1000 cols, fp32.
// Tier0: rel [0,50) vs neg [475,1000), /26250
// Tier1: rel [475,525) vs neg [950,1000), /2500
// GT:    rel [0,n) vs neg [n,1000), *2/1000, n<=8 (wave-uniform per row)
//
// R8: direct-VALU rewrite of the per-row math.
//  - R7 proved the 44 us / 256 MiB fillBufferAligned is an UNCONDITIONAL
//    harness workspace poison (present with d_ws untouched). Plumbing reverted
//    to R6's partials-in-d_ws + tiny second reduce kernel (atomics cost +10us).
//  - R6's sort/prefix/binary-search engine was latency-bound: ~140 LDS-pipe
//    shuffles per wave, long dependent chains, only 4 waves/SIMD to hide them
//    (4096 rows = 4096 waves, hard cap). Window VALUBusy ~4%.
//  - New math: relu(x - m) = max(x, m) - m, so
//        sum_k relu(x - m_k) = sum_k max(x, m_k) - S,   S = sum_k m_k
//    with m_k = r_k - 1. Inner pair = 2 VALU ops, ZERO shuffles/sort/search.
//    Relatives broadcast via v_readlane (literal lane index, unrolled).
//    Inactive (slot,lane) pairs poisoned with -FLT_MAX: max(-FLT_MAX,m)-m = 0,
//    so masking is free and the uniform "- count*S" correction stays exact.
//  - ~1650 VALU/wave, 9-16 independent acc chains -> VALU-throughput-bound.

#define BQ 4096
#define DQ 1000
#define GRID 1024   // 4 rows/block, 1 row/wave

__device__ __forceinline__ float rdlane(float v, int l) {
    return __int_as_float(__builtin_amdgcn_readlane(__float_as_int(v), l));
}

__global__ __launch_bounds__(256) void mtl_rows(const float* __restrict__ scores,
                                               const int* __restrict__ labels,
                                               float* __restrict__ partials) {
    const int tid  = threadIdx.x;
    const int lane = tid & 63;
    const int w    = tid >> 6;
    const int row  = blockIdx.x * 4 + w;
    const float* sr = scores + (size_t)row * DQ;

    __shared__ float wsum[4];

    const float NEG = -FLT_MAX;

    // round-robin register row: q[t] = s[lane + 64t]
    float q[16];
    #pragma unroll
    for (int t = 0; t < 15; ++t) q[t] = sr[lane + 64 * t];
    q[15] = (lane < 40) ? sr[960 + lane] : NEG;    // poison j>=1000 (zeroes all uses)

    // n from first 8 labels via ballot (n <= MAX_REL = 8 by construction)
    int lv = -1;
    if (lane < 8) lv = labels[(size_t)row * DQ + lane];
    const int n = __popcll(__ballot(lv > -1));     // wave-uniform

    // masked slot views (poisoned lanes contribute exactly 0)
    const float x7t0  = (lane >= 27) ? q[7]  : NEG;   // tier0 neg j>=475
    const float x14t1 = (lane >= 54) ? q[14] : NEG;   // tier1 neg j>=950
    const float x0g   = (lane >= n)  ? q[0]  : NEG;   // GT    neg j>=n

    // ---- tier0: rels s[0..50) = q[0] lanes 0..49; negs slots 7..15
    float a0[9];
    #pragma unroll
    for (int i = 0; i < 9; ++i) a0[i] = 0.0f;
    float S0 = 0.0f;
    #pragma unroll
    for (int k = 0; k < 50; ++k) {
        const float m = rdlane(q[0], k) - 1.0f;
        S0 += m;
        a0[0] += fmaxf(x7t0, m);
        #pragma unroll
        for (int t = 8; t < 15; ++t) a0[t - 7] += fmaxf(q[t], m);
        a0[8] += fmaxf(q[15], m);
    }
    float t0 = ((a0[0] + a0[1]) + (a0[2] + a0[3]))
             + ((a0[4] + a0[5]) + (a0[6] + a0[7])) + a0[8]
             - 9.0f * S0;

    // ---- tier1: rels s[475..525) = q[7] lanes 27..63 + q[8] lanes 0..12
    float a1a = 0.0f, a1b = 0.0f, S1 = 0.0f;
    #pragma unroll
    for (int k = 0; k < 37; ++k) {
        const float m = rdlane(q[7], 27 + k) - 1.0f;
        S1 += m;
        a1a += fmaxf(x14t1, m);
        a1b += fmaxf(q[15], m);
    }
    #pragma unroll
    for (int k = 0; k < 13; ++k) {
        const float m = rdlane(q[8], k) - 1.0f;
        S1 += m;
        a1a += fmaxf(x14t1, m);
        a1b += fmaxf(q[15], m);
    }
    float t1 = (a1a + a1b) - 2.0f * S1;

    // ---- GT: rels s[0..n) = q[0] lanes 0..n-1; negs all 16 slots (x0g masked)
    float gtacc = 0.0f, Sg = 0.0f;
    for (int k = 0; k < n; ++k) {                  // uniform trip count, n<=8
        const float m = rdlane(q[0], k) - 1.0f;
        Sg += m;
        float h0 = fmaxf(x0g,  m);
        float h1 = fmaxf(q[1], m);
        float h2 = fmaxf(q[2], m);
        float h3 = fmaxf(q[3], m);
        #pragma unroll
        for (int t = 4; t < 16; t += 4) {
            h0 += fmaxf(q[t],     m);
            h1 += fmaxf(q[t + 1], m);
            h2 += fmaxf(q[t + 2], m);
            h3 += fmaxf(q[t + 3], m);
        }
        gtacc += (h0 + h1) + (h2 + h3);
    }
    float gt = gtacc - 16.0f * Sg;

    float acc = t0 * (1.0f / 26250.0f)
              + t1 * (1.0f / 2500.0f)
              + gt * (2.0f / 1000.0f);

    // ---- wave reduce, then fold the block's 4 waves -> one partial
    #pragma unroll
    for (int off = 32; off > 0; off >>= 1) acc += __shfl_down(acc, off, 64);
    if (lane == 0) wsum[w] = acc;
    __syncthreads();
    if (tid == 0) partials[blockIdx.x] = wsum[0] + wsum[1] + wsum[2] + wsum[3];
}

__global__ __launch_bounds__(256) void mtl_reduce_kernel(const float* __restrict__ partials,
                                                         float* __restrict__ out) {
    __shared__ float wsum[4];
    const int tid  = threadIdx.x;
    float acc = partials[tid] + partials[tid + 256]
              + partials[tid + 512] + partials[tid + 768];
    #pragma unroll
    for (int off = 32; off > 0; off >>= 1) acc += __shfl_down(acc, off, 64);
    const int lane = tid & 63;
    const int wid  = tid >> 6;
    if (lane == 0) wsum[wid] = acc;
    __syncthreads();
    if (tid == 0) out[0] = (wsum[0] + wsum[1] + wsum[2] + wsum[3]) * (1.0f / (float)BQ);
}

extern "C" void kernel_launch(void* const* d_in, const int* in_sizes, int n_in,
                              void* d_out, int out_size, void* d_ws, size_t ws_size,
                              hipStream_t stream) {
    const float* scores = (const float*)d_in[0];
    const int*   labels = (const int*)d_in[1];
    float* partials = (float*)d_ws;      // 4 KB scratch
    float* out = (float*)d_out;

    mtl_rows<<<GRID, 256, 0, stream>>>(scores, labels, partials);
    mtl_reduce_kernel<<<1, 256, 0, stream>>>(partials, out);
}

// Round 3
// 79.531 us; speedup vs baseline: 1.1350x; 1.0652x over previous
//
#include <hip/hip_runtime.h>
#include <float.h>

// MultiTierLoss: B=4096 rows, D=1000 cols, fp32.
// Tier0: rel [0,50) vs neg [475,1000), /26250
// Tier1: rel [475,525) vs neg [950,1000), /2500
// GT:    rel [0,n) vs neg [n,1000), *2/1000, n<=8 (wave-uniform per row)
//
// R9 = R6 restored (measured best: 79.6 us), + GT broadcast via v_readlane.
// Session ledger:
//  - R7: 44 us / 256 MiB fillBufferAligned is UNCONDITIONAL harness ws poison
//    (present with d_ws untouched). Same-address atomic fan-in costs +10 us vs
//    +4 us for a second reduce dispatch (confirms R3/R5). Keep two kernels.
//  - R8: brute-VALU max-identity (no sort) is ~5 us SLOWER than sort+search:
//    ~1700 VALU/wave vs ~90 DS + ~500 VALU/wave; DS latency pipelines fine
//    across 4 waves/SIMD x 9 independent searches. Reverted.
//  - Window decomposition: 44 fill + ~25-30 harness resets + ~8-10 us ours.
//
// Structure: ONE ROW PER WAVE, zero LDS in hot path, zero barriers till epilogue.
//  - Row in registers round-robin q[t] = sr[lane + 64t].
//  - sum_i relu(x - r_i) over sorted relatives = c*x - pre[c]; sort via
//    21-stage register bitonic (__shfl_xor), prefix via shuffle scan,
//    c via 6-step shuffle binary search.
//  - Block folds its 4 wave sums -> ONE partial per block (d_ws).
//  - Tiny second kernel reduces.

#define BQ 4096
#define DQ 1000
#define GRID 1024   // 4 rows/block, 1 row/wave

__device__ __forceinline__ float rdlane(float v, int l) {   // l wave-uniform
    return __int_as_float(__builtin_amdgcn_readlane(__float_as_int(v), l));
}

__device__ __forceinline__ float bitonic_sort64(float v, int lane) {
    #pragma unroll
    for (int size = 2; size <= 64; size <<= 1) {
        #pragma unroll
        for (int stride = size >> 1; stride > 0; stride >>= 1) {
            float other = __shfl_xor(v, stride, 64);
            bool keep_min = (((lane & stride) == 0) == ((lane & size) == 0));
            v = keep_min ? fminf(v, other) : fmaxf(v, other);
        }
    }
    return v;   // ascending across lanes 0..63
}

__device__ __forceinline__ float excl_scan50(float sv, int lane) {
    float x = (lane < 50) ? sv : 0.0f;   // zero the FLT_MAX pads
    float inc = x;
    #pragma unroll
    for (int off = 1; off < 64; off <<= 1) {
        float t = __shfl_up(inc, off, 64);
        if (lane >= off) inc += t;
    }
    return inc - x;   // lane c holds sum of sorted[0..c)
}

// sum_i relu(x - sorted_i) = c*x - pre[c], c = #{sorted_i < x} (<=50)
__device__ __forceinline__ float sorted_relu_sum(float x, float sv, float pre) {
    int c = 0;
    #pragma unroll
    for (int st = 32; st >= 1; st >>= 1) {
        float scv = __shfl(sv, c + st - 1, 64);   // pads=FLT_MAX cap c at 50
        c += (scv < x) ? st : 0;
    }
    float p = __shfl(pre, c, 64);
    return (float)c * x - p;
}

__global__ __launch_bounds__(256) void mtl_rows(const float* __restrict__ scores,
                                               const int* __restrict__ labels,
                                               float* __restrict__ partials) {
    const int tid  = threadIdx.x;
    const int lane = tid & 63;
    const int w    = tid >> 6;
    const int row  = blockIdx.x * 4 + w;
    const float* sr = scores + (size_t)row * DQ;

    __shared__ float wsum[4];

    // round-robin register row: q[t] = s[lane + 64t]
    float q[16];
    #pragma unroll
    for (int t = 0; t < 15; ++t) q[t] = sr[lane + 64 * t];
    q[15] = (lane < 40) ? sr[960 + lane] : 0.0f;   // j=960+lane < 1000

    // n from first 8 labels via ballot (n <= MAX_REL = 8 by construction)
    int lv = -1;
    if (lane < 8) lv = labels[(size_t)row * DQ + lane];
    const int n = __popcll(__ballot(lv > -1));     // wave-uniform

    // tier0 relatives s[0..50) == q[0] on lanes 0..49
    float sv0  = bitonic_sort64((lane < 50) ? q[0] : FLT_MAX, lane);
    float pre0 = excl_scan50(sv0, lane);

    // tier1 relatives s[475..525)
    float r1 = FLT_MAX;
    if (lane < 50) r1 = sr[475 + lane];
    float sv1  = bitonic_sort64(r1, lane);
    float pre1 = excl_scan50(sv1, lane);

    // ---- GT: x_j = 1 + s_j, relatives s[0..n) broadcast via v_readlane
    float tgt[16];
    #pragma unroll
    for (int t = 0; t < 16; ++t) tgt[t] = 0.0f;
    for (int k = 0; k < n; ++k) {                  // uniform trip count
        float gk = 1.0f - rdlane(q[0], k);         // VALU readlane, no DS op
        #pragma unroll
        for (int t = 0; t < 16; ++t) tgt[t] += fmaxf(q[t] + gk, 0.0f);
    }
    float gts = (lane >= n) ? tgt[0] : 0.0f;       // slot 0: j=lane, need j>=n
    #pragma unroll
    for (int t = 1; t < 15; ++t) gts += tgt[t];    // j in [64,960) all valid
    gts += (lane < 40) ? tgt[15] : 0.0f;           // j<1000
    float acc = gts * (2.0f / 1000.0f);

    // ---- tier0: negatives j in [475,1000) -> slots 7..15
    float t0s = 0.0f;
    #pragma unroll
    for (int t = 7; t < 16; ++t) {
        float x = 1.0f + q[t];
        float val = sorted_relu_sum(x, sv0, pre0);
        bool act = (t == 7) ? (lane >= 27)         // j=448+lane >= 475
                 : (t == 15) ? (lane < 40)         // j=960+lane < 1000
                 : true;
        t0s += act ? val : 0.0f;
    }
    acc += t0s * (1.0f / 26250.0f);

    // ---- tier1: negatives j in [950,1000) -> slots 14 (lane>=54), 15 (lane<40)
    {
        float v14 = sorted_relu_sum(1.0f + q[14], sv1, pre1);
        acc += (lane >= 54) ? v14 * (1.0f / 2500.0f) : 0.0f;
        float v15 = sorted_relu_sum(1.0f + q[15], sv1, pre1);
        acc += (lane < 40) ? v15 * (1.0f / 2500.0f) : 0.0f;
    }

    // ---- wave reduce, then fold the block's 4 waves -> one partial
    #pragma unroll
    for (int off = 32; off > 0; off >>= 1) acc += __shfl_down(acc, off, 64);
    if (lane == 0) wsum[w] = acc;
    __syncthreads();
    if (tid == 0) partials[blockIdx.x] = wsum[0] + wsum[1] + wsum[2] + wsum[3];
}

__global__ __launch_bounds__(256) void mtl_reduce_kernel(const float* __restrict__ partials,
                                                         float* __restrict__ out) {
    __shared__ float wsum[4];
    const int tid  = threadIdx.x;
    float acc = partials[tid] + partials[tid + 256]
              + partials[tid + 512] + partials[tid + 768];
    #pragma unroll
    for (int off = 32; off > 0; off >>= 1) acc += __shfl_down(acc, off, 64);
    const int lane = tid & 63;
    const int wid  = tid >> 6;
    if (lane == 0) wsum[wid] = acc;
    __syncthreads();
    if (tid == 0) out[0] = (wsum[0] + wsum[1] + wsum[2] + wsum[3]) * (1.0f / (float)BQ);
}

extern "C" void kernel_launch(void* const* d_in, const int* in_sizes, int n_in,
                              void* d_out, int out_size, void* d_ws, size_t ws_size,
                              hipStream_t stream) {
    const float* scores = (const float*)d_in[0];
    const int*   labels = (const int*)d_in[1];
    float* partials = (float*)d_ws;      // 4 KB scratch
    float* out = (float*)d_out;

    mtl_rows<<<GRID, 256, 0, stream>>>(scores, labels, partials);
    mtl_reduce_kernel<<<1, 256, 0, stream>>>(partials, out);
}